// Round 4
// baseline (612.797 us; speedup 1.0000x reference)
//
#include <hip/hip_runtime.h>
#include <math.h>

typedef float2 cplx;

#define TPB 256
#define IN_DIM 4000
#define NREPS 4

// 1/k! coefficients
#define C3f  0.16666667f
#define C4f  0.041666668f
#define C5f  8.3333333e-3f
#define C6f  1.3888889e-3f
#define C7f  1.9841270e-4f
#define C8f  2.4801587e-5f
#define C9f  2.7557319e-6f
#define C10f 2.7557319e-7f
#define C11f 2.5052108e-8f
#define C12f 2.0876757e-9f
#define C13f 1.6059044e-10f

// ---------------------------------------------------------------------------
// X ("plain-swizzled"): logical (r,c) at X[r*64 + (c ^ (((c>>4)&1)<<1))]
//   (16B chunk k of a row at physical chunk k ^ ((k>>3)&1)) -> 2-way = free.
// Y ("transposed-swizzled"): logical YT[m][r] = L[r][m] at Y[m*64 + (r ^ S(m))],
//   S(m) = ((m>>2)&7)<<1 (even -> preserves aligned 16B pairs).
// Thread tiling: ri = t>>4, ci = t&15; 4x4 tile rows 4ri.., cols 4ci.. .
// mm computes C = L * R with L read from Y, R read from X. All b128, no
// register tiles held across the k-loop except the accumulator (+ A-tile).
// ---------------------------------------------------------------------------

__device__ __forceinline__ void mm_step(const cplx* __restrict__ X,
                                        const cplx* __restrict__ Y,
                                        int ri, int c1, int c2,
                                        float* __restrict__ cre,
                                        float* __restrict__ cim)
{
    #pragma unroll 8
    for (int kk = 0; kk < 64; kk++) {
        int sa = ((kk >> 2) & 7) << 1;
        const float4* Yrow = (const float4*)(Y + (kk << 6));
        int pa = (((ri << 2) ^ sa) >> 1);
        float4 a01 = Yrow[pa];          // L[4ri+0][kk], L[4ri+1][kk]
        float4 a23 = Yrow[pa ^ 1];      // L[4ri+2][kk], L[4ri+3][kk]
        const float4* Xrow = (const float4*)(X + (kk << 6));
        float4 b01 = Xrow[c1];          // R[kk][4ci+0,1]
        float4 b23 = Xrow[c2];          // R[kk][4ci+2,3]

        float ar0 = a01.x, ai0 = a01.y, ar1 = a01.z, ai1 = a01.w;
        float ar2 = a23.x, ai2 = a23.y, ar3 = a23.z, ai3 = a23.w;
        float br0 = b01.x, bi0 = b01.y, br1 = b01.z, bi1 = b01.w;
        float br2 = b23.x, bi2 = b23.y, br3 = b23.z, bi3 = b23.w;

        #define CF(id, AR, AI, BR, BI)                                    \
            cre[id] = fmaf(AR, BR, fmaf(-(AI), (BI), cre[id]));           \
            cim[id] = fmaf(AR, BI, fmaf((AI), (BR), cim[id]));
        CF( 0, ar0, ai0, br0, bi0)  CF( 1, ar0, ai0, br1, bi1)
        CF( 2, ar0, ai0, br2, bi2)  CF( 3, ar0, ai0, br3, bi3)
        CF( 4, ar1, ai1, br0, bi0)  CF( 5, ar1, ai1, br1, bi1)
        CF( 6, ar1, ai1, br2, bi2)  CF( 7, ar1, ai1, br3, bi3)
        CF( 8, ar2, ai2, br0, bi0)  CF( 9, ar2, ai2, br1, bi1)
        CF(10, ar2, ai2, br2, bi2)  CF(11, ar2, ai2, br3, bi3)
        CF(12, ar3, ai3, br0, bi0)  CF(13, ar3, ai3, br1, bi1)
        CF(14, ar3, ai3, br2, bi2)  CF(15, ar3, ai3, br3, bi3)
        #undef CF
    }
}

// Write 4x4 tile into Y (transposed-swizzled)
__device__ __forceinline__ void writeYT(cplx* __restrict__ Y, int ri, int ci,
                                        const float* __restrict__ vre,
                                        const float* __restrict__ vim)
{
    const int sb = (ci & 7) << 1;
    const int p = (((ri << 2) ^ sb) >> 1);
    #pragma unroll
    for (int dc = 0; dc < 4; dc++) {
        float4* Yrow = (float4*)(Y + (((ci << 2) + dc) << 6));
        Yrow[p]     = make_float4(vre[dc], vim[dc], vre[4 + dc], vim[4 + dc]);
        Yrow[p ^ 1] = make_float4(vre[8 + dc], vim[8 + dc], vre[12 + dc], vim[12 + dc]);
    }
}

// Write 4x4 tile into X (plain-swizzled)
__device__ __forceinline__ void writeXtile(cplx* __restrict__ X, int ri, int c1, int c2,
                                           const float* __restrict__ vre,
                                           const float* __restrict__ vim)
{
    #pragma unroll
    for (int dr = 0; dr < 4; dr++) {
        float4* Xrow = (float4*)(X + (((ri << 2) + dr) << 6));
        Xrow[c1] = make_float4(vre[dr*4+0], vim[dr*4+0], vre[dr*4+1], vim[dr*4+1]);
        Xrow[c2] = make_float4(vre[dr*4+2], vim[dr*4+2], vre[dr*4+3], vim[dr*4+3]);
    }
}

// Precondition: X[m*64+z] (UNswizzled) = D[m][z] = c_{(m,z)} * (-i)^popc(m&z);
// sumsq = per-thread partial of sum c^2.
// Postcondition: X = exp(-iH) in plain-swizzled layout. Y scratch. red: 256 floats.
__device__ void expm_core(cplx* X, cplx* Y, float* red, int t, float sumsq)
{
    const int ri = t >> 4, ci = t & 15;
    const int xb = (ci >> 2) & 1;
    const int c1 = (ci << 1) + xb;
    const int c2 = (ci << 1) + 1 - xb;

    // ---- reduce sum(c^2) -> ||H||_F = sqrt(64*sum c^2) >= ||H||_2 ----
    red[t] = sumsq;
    __syncthreads();
    for (int off = 128; off >= 1; off >>= 1) {
        if (t < off) red[t] += red[t + off];
        __syncthreads();
    }
    float fro = sqrtf(64.0f * red[0]);
    __syncthreads();
    // preliminary scaling: ||B||_2 <= fro/2^s1 in (4,8]
    int s1 = 0; { float nn = fro; while (nn > 8.0f && s1 < 24) { nn *= 0.5f; s1++; } }
    float sc1 = exp2f((float)(-s1));

    // ---- WHT over z within each row m ----
    for (int st = 0; st < 6; st++) {
        int len = 1 << st;
        #pragma unroll
        for (int n = 0; n < 8; n++) {
            int q = t + TPB * n;
            int m = q >> 5, bf = q & 31;
            int lo = bf & (len - 1), hi = bf >> st;
            int z0 = (hi << (st + 1)) | lo;
            int z1 = z0 | len;
            cplx a = X[(m << 6) + z0], b = X[(m << 6) + z1];
            X[(m << 6) + z0] = make_float2(a.x + b.x, a.y + b.y);
            X[(m << 6) + z1] = make_float2(a.x - b.x, a.y - b.y);
        }
        __syncthreads();
    }

    // ---- scatter: B[i][i^m] = -i*h_m(i)*2^-s1;  X <- B (swz), Y <- B^T (swz) ----
    cplx hv[16];
    #pragma unroll
    for (int n = 0; n < 16; n++) hv[n] = X[t + TPB * n];
    __syncthreads();
    #pragma unroll
    for (int n = 0; n < 16; n++) {
        int idx = t + TPB * n;
        int m = idx >> 6, i = idx & 63;
        cplx av = make_float2(hv[n].y * sc1, -hv[n].x * sc1);
        int r = i, c = i ^ m;
        X[(r << 6) + (c ^ (((c >> 4) & 1) << 1))] = av;
        Y[(c << 6) + (r ^ (((c >> 2) & 7) << 1))] = av;
    }
    __syncthreads();

    float cre[16], cim[16];
    #define ZERO_C  _Pragma("unroll") for (int id = 0; id < 16; id++) { cre[id] = 0.f; cim[id] = 0.f; }
    const bool onDiag = (ri == ci);

    // ---- mm1: B2 = B*B (L=B from Y, R=B from X) ----
    ZERO_C
    mm_step(X, Y, ri, c1, c2, cre, cim);

    // ---- Schatten-4 bound: ||B||_2 <= sqrt(||B2||_F) ----
    float ss = 0.f;
    #pragma unroll
    for (int id = 0; id < 16; id++) ss += cre[id]*cre[id] + cim[id]*cim[id];
    __syncthreads();                       // all mm reads of X,Y done
    red[t] = ss;
    __syncthreads();
    for (int off = 128; off >= 1; off >>= 1) {
        if (t < off) red[t] += red[t + off];
        __syncthreads();
    }
    float bound = sqrtf(sqrtf(red[0]));    // (||B2||_F^2)^(1/4) = S4 >= ||B||_2
    int ds = 0; { float nn = bound; while (nn > 2.0f && ds < 10) { nn *= 0.5f; ds++; } }
    const int s = s1 + ds;                 // total squarings; theta = 2
    float dsc = exp2f((float)(-ds)), dsc2 = dsc * dsc;

    // ---- A-tile (final-scaled) into regs; held across Horner ----
    float are[16], aim[16];
    #pragma unroll
    for (int dr = 0; dr < 4; dr++) {
        const float4* Xrow = (const float4*)(X + (((ri << 2) + dr) << 6));
        float4 x01 = Xrow[c1], x23 = Xrow[c2];
        are[dr*4+0] = x01.x * dsc; aim[dr*4+0] = x01.y * dsc;
        are[dr*4+1] = x01.z * dsc; aim[dr*4+1] = x01.w * dsc;
        are[dr*4+2] = x23.x * dsc; aim[dr*4+2] = x23.y * dsc;
        are[dr*4+3] = x23.z * dsc; aim[dr*4+3] = x23.w * dsc;
    }

    // ---- Y <- A2^T = (B2 * dsc^2)^T  (static left operand for Horner) ----
    #pragma unroll
    for (int id = 0; id < 16; id++) { cre[id] *= dsc2; cim[id] *= dsc2; }
    writeYT(Y, ri, ci, cre, cim);

    // ---- X <- V6 = c12 I + c13 A ----
    #pragma unroll
    for (int id = 0; id < 16; id++) { cre[id] = C13f * are[id]; cim[id] = C13f * aim[id]; }
    if (onDiag) { cre[0] += C12f; cre[5] += C12f; cre[10] += C12f; cre[15] += C12f; }
    writeXtile(X, ri, c1, c2, cre, cim);
    __syncthreads();

    // ---- Horner: V_j = c_{2j} I + c_{2j+1} A + A2 * V_{j+1},  j = 5..0 ----
    const float cIc[6] = { 1.0f, 0.5f, C4f, C6f, C8f, C10f };
    const float cAc[6] = { 1.0f, C3f,  C5f, C7f, C9f, C11f };
    #pragma unroll
    for (int j = 5; j >= 0; j--) {
        ZERO_C
        mm_step(X, Y, ri, c1, c2, cre, cim);    // C = A2 * V_{j+1}
        __syncthreads();                        // X reads done before overwrite
        float ca = cAc[j], cI = cIc[j];
        #pragma unroll
        for (int id = 0; id < 16; id++) {
            cre[id] = fmaf(ca, are[id], cre[id]);
            cim[id] = fmaf(ca, aim[id], cim[id]);
        }
        if (onDiag) { cre[0] += cI; cre[5] += cI; cre[10] += cI; cre[15] += cI; }
        writeXtile(X, ri, c1, c2, cre, cim);    // V_j -> X
        __syncthreads();
    }
    // regs cre/cim = U, X = U (plain-swz)

    // ---- s squarings: U <- U*U (L=U via Y, R=U via X) ----
    for (int q = 0; q < s; q++) {
        writeYT(Y, ri, ci, cre, cim);           // Y <- U^T (prior Y readers synced)
        __syncthreads();
        ZERO_C
        mm_step(X, Y, ri, c1, c2, cre, cim);
        __syncthreads();
        writeXtile(X, ri, c1, c2, cre, cim);    // X <- U^2 (readers done)
    }
    __syncthreads();
    #undef ZERO_C
}

// Pauli index p -> (xmask, zmask)
__device__ __forceinline__ void pauli_masks(int p, int& xm, int& zm) {
    xm = 0; zm = 0;
    #pragma unroll
    for (int k = 0; k < 6; k++) {
        int lo = (p >> (2 * k)) & 1;
        int hi = (p >> (2 * k + 1)) & 1;
        zm |= hi << k;
        xm |= (hi ^ lo) << k;
    }
}

__device__ __forceinline__ cplx pauli_phase(float v, int xm, int zm) {
    int ny = __popc(xm & zm) & 3;
    if (ny == 0) return make_float2(v, 0.f);
    if (ny == 1) return make_float2(0.f, -v);
    if (ny == 2) return make_float2(-v, 0.f);
    return make_float2(0.f, v);
}

// D-matrix loaders (X unswizzled): return per-thread sumsq partial
__device__ __forceinline__ float load_D_x(const float* __restrict__ xrow,
                                          cplx* __restrict__ X, int t)
{
    float sumsq = 0.f;
    #pragma unroll
    for (int n = 0; n < 16; n++) {
        int p = t + TPB * n;
        float v = (p < IN_DIM) ? xrow[p] : 0.f;
        sumsq += v * v;
        int xm, zm; pauli_masks(p, xm, zm);
        X[(xm << 6) + zm] = pauli_phase(v, xm, zm);
    }
    return sumsq;
}

__device__ __forceinline__ float load_D_w(const float* __restrict__ wrow,
                                          cplx* __restrict__ X, int t)
{
    float sumsq = 0.f;
    #pragma unroll
    for (int n = 0; n < 16; n++) {
        int p = t + TPB * n;
        float v = (p == 0) ? 0.f : wrow[p - 1];
        sumsq += v * v;
        int xm, zm; pauli_masks(p, xm, zm);
        X[(xm << 6) + zm] = pauli_phase(v, xm, zm);
    }
    return sumsq;
}

// acc = M[i][:] . pin ; M in plain-swizzled layout; chunk rotation spreads rows
__device__ __forceinline__ cplx matvec_row(const cplx* __restrict__ M,
                                           const cplx* __restrict__ pin, int i)
{
    float ax = 0.f, ay = 0.f;
    const float4* Mr = (const float4*)(M + (i << 6));
    #pragma unroll
    for (int mm = 0; mm < 16; mm++) {
        int ch = (mm + (i & 15)) & 15;
        int b = (ch >> 2) & 1;
        float4 m01 = Mr[(ch << 1) + b];
        float4 m23 = Mr[(ch << 1) + 1 - b];
        const cplx* p = pin + (ch << 2);
        cplx p0 = p[0], p1 = p[1], p2 = p[2], p3 = p[3];
        ax = fmaf(m01.x, p0.x, fmaf(-m01.y, p0.y, ax));
        ay = fmaf(m01.x, p0.y, fmaf( m01.y, p0.x, ay));
        ax = fmaf(m01.z, p1.x, fmaf(-m01.w, p1.y, ax));
        ay = fmaf(m01.z, p1.y, fmaf( m01.w, p1.x, ay));
        ax = fmaf(m23.x, p2.x, fmaf(-m23.y, p2.y, ax));
        ay = fmaf(m23.x, p2.y, fmaf( m23.y, p2.x, ay));
        ax = fmaf(m23.z, p3.x, fmaf(-m23.w, p3.y, ax));
        ay = fmaf(m23.z, p3.y, fmaf( m23.w, p3.x, ay));
    }
    return make_float2(ax, ay);
}

// ===== split path: all expms in one overlapped launch, then matvecs =====
// ws slots (4096 cplx each): [0..B) = Ud[sample], [B..B+4) = Up[rep]
__global__ __launch_bounds__(TPB) void expm_all_kernel(const float* __restrict__ x,
                                                       const float* __restrict__ w,
                                                       cplx* __restrict__ ws, int B)
{
    __shared__ float4 Xs4[2048];
    __shared__ float4 Ys4[2048];
    __shared__ float red[TPB];
    cplx* X = (cplx*)Xs4;
    cplx* Y = (cplx*)Ys4;
    int t = threadIdx.x, blk = blockIdx.x;
    float sumsq = (blk < B) ? load_D_x(x + (size_t)blk * IN_DIM, X, t)
                            : load_D_w(w + (size_t)(blk - B) * 4095, X, t);
    __syncthreads();
    expm_core(X, Y, red, t, sumsq);
    float4* dst = (float4*)(ws + ((size_t)blk << 12));
    const float4* src = (const float4*)X;
    #pragma unroll
    for (int n = 0; n < 8; n++) dst[n * TPB + t] = src[n * TPB + t];
}

__global__ __launch_bounds__(TPB) void matvec_kernel(const cplx* __restrict__ ws,
                                                     const float* __restrict__ bias,
                                                     float* __restrict__ out, int B)
{
    __shared__ float4 Xs4[2048];
    __shared__ float4 Ys4[2048];
    __shared__ cplx psiA[64], psiB[64];
    cplx* X = (cplx*)Xs4;
    cplx* Y = (cplx*)Ys4;
    int t = threadIdx.x, b = blockIdx.x;
    // stage Ud
    {
        const float4* src = (const float4*)(ws + ((size_t)b << 12));
        float4* dst = (float4*)X;
        #pragma unroll
        for (int n = 0; n < 8; n++) dst[n * TPB + t] = src[n * TPB + t];
    }
    if (t < 64) psiA[t] = make_float2(t == 0 ? 1.f : 0.f, 0.f);
    __syncthreads();
    for (int r = 0; r < NREPS; r++) {
        const float4* src = (const float4*)(ws + ((size_t)(B + r) << 12));
        float4* dstY = (float4*)Y;
        #pragma unroll
        for (int n = 0; n < 8; n++) dstY[n * TPB + t] = src[n * TPB + t];
        __syncthreads();
        if (t < 64) psiB[t] = matvec_row(X, psiA, t);
        __syncthreads();
        if (t < 64) psiA[t] = matvec_row(Y, psiB, t);
        __syncthreads();
    }
    if (t < 64) {
        cplx pv = psiA[t];
        out[(b << 6) + t] = fmaf(pv.x, pv.x, fmaf(pv.y, pv.y, bias[t]));
    }
}

// ===== fallback path (ws too small): serial up + fused circuit =====
__global__ __launch_bounds__(TPB) void up_only_kernel(const float* __restrict__ w,
                                                      cplx* __restrict__ up)
{
    __shared__ float4 Xs4[2048];
    __shared__ float4 Ys4[2048];
    __shared__ float red[TPB];
    cplx* X = (cplx*)Xs4;
    cplx* Y = (cplx*)Ys4;
    int t = threadIdx.x, r = blockIdx.x;
    float sumsq = load_D_w(w + (size_t)r * 4095, X, t);
    __syncthreads();
    expm_core(X, Y, red, t, sumsq);
    float4* dst = (float4*)(up + ((size_t)r << 12));
    const float4* src = (const float4*)X;
    #pragma unroll
    for (int n = 0; n < 8; n++) dst[n * TPB + t] = src[n * TPB + t];
}

__global__ __launch_bounds__(TPB) void fused_kernel(const float* __restrict__ x,
                                                    const cplx* __restrict__ up,
                                                    const float* __restrict__ bias,
                                                    float* __restrict__ out)
{
    __shared__ float4 Xs4[2048];
    __shared__ float4 Ys4[2048];
    __shared__ float red[TPB];
    __shared__ cplx psiA[64], psiB[64];
    cplx* X = (cplx*)Xs4;
    cplx* Y = (cplx*)Ys4;
    int t = threadIdx.x, b = blockIdx.x;
    float sumsq = load_D_x(x + (size_t)b * IN_DIM, X, t);
    __syncthreads();
    expm_core(X, Y, red, t, sumsq);     // X = Ud (plain-swz); Y free

    if (t < 64) psiA[t] = make_float2(t == 0 ? 1.f : 0.f, 0.f);
    __syncthreads();
    for (int r = 0; r < NREPS; r++) {
        const float4* src = (const float4*)(up + ((size_t)r << 12));
        float4* dstY = (float4*)Y;
        #pragma unroll
        for (int n = 0; n < 8; n++) dstY[n * TPB + t] = src[n * TPB + t];
        __syncthreads();
        if (t < 64) psiB[t] = matvec_row(X, psiA, t);
        __syncthreads();
        if (t < 64) psiA[t] = matvec_row(Y, psiB, t);
        __syncthreads();
    }
    if (t < 64) {
        cplx pv = psiA[t];
        out[(b << 6) + t] = fmaf(pv.x, pv.x, fmaf(pv.y, pv.y, bias[t]));
    }
}

extern "C" void kernel_launch(void* const* d_in, const int* in_sizes, int n_in,
                              void* d_out, int out_size, void* d_ws, size_t ws_size,
                              hipStream_t stream)
{
    const float* x    = (const float*)d_in[0];
    const float* w    = (const float*)d_in[1];
    const float* bias = (const float*)d_in[2];
    float* out = (float*)d_out;
    cplx* ws   = (cplx*)d_ws;

    int B = in_sizes[0] / IN_DIM;            // 512
    size_t need = (size_t)(B + NREPS) * 4096 * sizeof(cplx);   // ~16.9 MB

    if (ws_size >= need) {
        hipLaunchKernelGGL(expm_all_kernel, dim3(B + NREPS), dim3(TPB), 0, stream, x, w, ws, B);
        hipLaunchKernelGGL(matvec_kernel,   dim3(B),         dim3(TPB), 0, stream, ws, bias, out, B);
    } else {
        hipLaunchKernelGGL(up_only_kernel,  dim3(NREPS), dim3(TPB), 0, stream, w, ws);
        hipLaunchKernelGGL(fused_kernel,    dim3(B),     dim3(TPB), 0, stream, x, ws, bias, out);
    }
}

// Round 5
// 166.134 us; speedup vs baseline: 3.6886x; 3.6886x over previous
//
#include <hip/hip_runtime.h>
#include <math.h>

typedef float2 cplx;
typedef __attribute__((ext_vector_type(8))) short short8v;
typedef __attribute__((ext_vector_type(4))) short short4v;
typedef __attribute__((ext_vector_type(4))) float float4v;

#define TPB 256
#define IN_DIM 4000
#define NREPS 4

// 1/k! coefficients
#define C3f  0.16666667f
#define C4f  0.041666668f
#define C5f  8.3333333e-3f
#define C6f  1.3888889e-3f
#define C7f  1.9841270e-4f
#define C8f  2.4801587e-5f
#define C9f  2.7557319e-6f
#define C10f 2.7557319e-7f
#define C11f 2.5052108e-8f
#define C12f 2.0876757e-9f
#define C13f 1.6059044e-10f

#define MFMA(A,B,C) __builtin_amdgcn_mfma_f32_16x16x32_bf16((A),(B),(C),0,0,0)

// ---------------------------------------------------------------------------
// LDS map (66560 B): [0,32K) Yset = L row-major bf16 planes {re_hi,re_lo,im_hi,
// im_lo} (aliases the fp32 W matrix used by the WHT phase); [32K,64K) Xset =
// R column-major planes; [64K,65K) red. Planes are 64x64 bf16 (8 KB), rows of
// 8 16B-chunks rotated by row index -> balanced-bank b128 fragment reads.
// elem (a,b) of a plane: idxSw(a,b). Row-major: idxSw(r,c). Col-major (R^T):
// idxSw(c,r).
// mfma tiling: wave w covers 32x32 quadrant (mh=w&1 rows, nh=w>>1 cols) as
// 2x2 16x16 tiles. lane: li=lane&15, q=lane>>4.
//   A-frag: A[m=li][k=q*8+j]; B-frag: B[k=q*8+j][n=li]; D: col=li,row=q*4+reg.
// ---------------------------------------------------------------------------

__device__ __forceinline__ int idxSw(int a, int b) {
    return (a << 6) + ((((b >> 3) + a) & 7) << 3) + (b & 7);
}
__device__ __forceinline__ short f2bf(float f) {   // RNE to bf16
    unsigned u = __float_as_uint(f);
    return (short)((u + 0x7FFF + ((u >> 16) & 1)) >> 16);
}
__device__ __forceinline__ float bf2f(short s) {
    return __uint_as_float(((unsigned)(unsigned short)s) << 16);
}

// C = L * R (complex), L from Yset (row-major), R from Xset (col-major).
__device__ __forceinline__ void mm_mfma(const short* __restrict__ sh, int li, int q,
                                        int mh, int nh,
                                        float4v* __restrict__ accRR, float4v* __restrict__ accII,
                                        float4v* __restrict__ accRI, float4v* __restrict__ accIR)
{
    #pragma unroll
    for (int ks = 0; ks < 2; ks++) {
        const int ch = ks * 4 + q;
        short8v A[2][4];
        #pragma unroll
        for (int dm = 0; dm < 2; dm++) {
            int r = ((mh * 2 + dm) << 4) + li;
            int off = (r << 6) + (((ch + r) & 7) << 3);
            #pragma unroll
            for (int p = 0; p < 4; p++)
                A[dm][p] = *(const short8v*)(sh + p * 4096 + off);
        }
        #pragma unroll
        for (int dn = 0; dn < 2; dn++) {
            int n = ((nh * 2 + dn) << 4) + li;
            int off = (n << 6) + (((ch + n) & 7) << 3);
            short8v Brh = *(const short8v*)(sh + 16384 + off);
            short8v Brl = *(const short8v*)(sh + 16384 + 4096 + off);
            short8v Bih = *(const short8v*)(sh + 16384 + 8192 + off);
            short8v Bil = *(const short8v*)(sh + 16384 + 12288 + off);
            #pragma unroll
            for (int dm = 0; dm < 2; dm++) {
                int ti = dm * 2 + dn;
                short8v arh = A[dm][0], arl = A[dm][1];
                short8v aih = A[dm][2], ail = A[dm][3];
                accRR[ti] = MFMA(arh, Brh, accRR[ti]);
                accRR[ti] = MFMA(arh, Brl, accRR[ti]);
                accRR[ti] = MFMA(arl, Brh, accRR[ti]);
                accII[ti] = MFMA(aih, Bih, accII[ti]);
                accII[ti] = MFMA(aih, Bil, accII[ti]);
                accII[ti] = MFMA(ail, Bih, accII[ti]);
                accRI[ti] = MFMA(arh, Bih, accRI[ti]);
                accRI[ti] = MFMA(arh, Bil, accRI[ti]);
                accRI[ti] = MFMA(arl, Bih, accRI[ti]);
                accIR[ti] = MFMA(aih, Brh, accIR[ti]);
                accIR[ti] = MFMA(aih, Brl, accIR[ti]);
                accIR[ti] = MFMA(ail, Brh, accIR[ti]);
            }
        }
    }
}

// write lane's C-tiles into Yset (row-major) as bf16 hi/lo — b16 scatter
__device__ __forceinline__ void write_row(short* __restrict__ sh, int li, int q,
                                          int mh, int nh,
                                          const float4v* cre, const float4v* cim)
{
    #pragma unroll
    for (int dm = 0; dm < 2; dm++)
    #pragma unroll
    for (int dn = 0; dn < 2; dn++) {
        int ti = dm * 2 + dn;
        int c = ((nh * 2 + dn) << 4) + li;
        #pragma unroll
        for (int reg = 0; reg < 4; reg++) {
            int r = ((mh * 2 + dm) << 4) + q * 4 + reg;
            int off = idxSw(r, c);
            float vr = cre[ti][reg], vi = cim[ti][reg];
            short rh = f2bf(vr); short rl = f2bf(vr - bf2f(rh));
            short ih = f2bf(vi); short il = f2bf(vi - bf2f(ih));
            sh[off] = rh; sh[4096 + off] = rl;
            sh[8192 + off] = ih; sh[12288 + off] = il;
        }
    }
}

// write lane's C-tiles into Xset (col-major) as bf16 hi/lo — packed b64
__device__ __forceinline__ void write_col(short* __restrict__ sh, int li, int q,
                                          int mh, int nh,
                                          const float4v* cre, const float4v* cim)
{
    #pragma unroll
    for (int dm = 0; dm < 2; dm++)
    #pragma unroll
    for (int dn = 0; dn < 2; dn++) {
        int ti = dm * 2 + dn;
        int c = ((nh * 2 + dn) << 4) + li;
        int k0 = ((mh * 2 + dm) << 4) + q * 4;
        int off = idxSw(c, k0);
        short4v rh, rl, ih, il;
        #pragma unroll
        for (int reg = 0; reg < 4; reg++) {
            float vr = cre[ti][reg], vi = cim[ti][reg];
            short h1 = f2bf(vr); rh[reg] = h1; rl[reg] = f2bf(vr - bf2f(h1));
            short h2 = f2bf(vi); ih[reg] = h2; il[reg] = f2bf(vi - bf2f(h2));
        }
        *(short4v*)(sh + 16384 + off) = rh;
        *(short4v*)(sh + 16384 + 4096 + off) = rl;
        *(short4v*)(sh + 16384 + 8192 + off) = ih;
        *(short4v*)(sh + 16384 + 12288 + off) = il;
    }
}

// gather lane's C-layout tile of the matrix currently in Yset (hi+lo)
__device__ __forceinline__ void gather_tile(const short* __restrict__ sh, int li, int q,
                                            int mh, int nh, float4v* bre, float4v* bim)
{
    #pragma unroll
    for (int dm = 0; dm < 2; dm++)
    #pragma unroll
    for (int dn = 0; dn < 2; dn++) {
        int ti = dm * 2 + dn;
        int c = ((nh * 2 + dn) << 4) + li;
        #pragma unroll
        for (int reg = 0; reg < 4; reg++) {
            int r = ((mh * 2 + dm) << 4) + q * 4 + reg;
            int off = idxSw(r, c);
            bre[ti][reg] = bf2f(sh[off]) + bf2f(sh[4096 + off]);
            bim[ti][reg] = bf2f(sh[8192 + off]) + bf2f(sh[12288 + off]);
        }
    }
}

__device__ __forceinline__ void adddiag(float4v* ure, float cI, int li, int q, int mh, int nh)
{
    #pragma unroll
    for (int dm = 0; dm < 2; dm++)
    #pragma unroll
    for (int dn = 0; dn < 2; dn++) {
        if (2 * mh + dm == 2 * nh + dn) {
            #pragma unroll
            for (int e = 0; e < 4; e++)
                if (li == q * 4 + e) ure[dm * 2 + dn][e] += cI;
        }
    }
}

// Pauli index p -> (xmask, zmask); phase = (-i)^popc(x&z)
__device__ __forceinline__ void pauli_masks(int p, int& xm, int& zm) {
    xm = 0; zm = 0;
    #pragma unroll
    for (int k = 0; k < 6; k++) {
        int lo = (p >> (2 * k)) & 1;
        int hi = (p >> (2 * k + 1)) & 1;
        zm |= hi << k;
        xm |= (hi ^ lo) << k;
    }
}
__device__ __forceinline__ cplx pauli_phase(float v, int xm, int zm) {
    int ny = __popc(xm & zm) & 3;
    if (ny == 0) return make_float2(v, 0.f);
    if (ny == 1) return make_float2(0.f, -v);
    if (ny == 2) return make_float2(-v, 0.f);
    return make_float2(0.f, v);
}

// ===== expm: one block per Hamiltonian; blocks [0,B) = Ud, [B,B+4) = Up =====
__global__ __launch_bounds__(TPB) void expm_mfma_kernel(const float* __restrict__ x,
                                                        const float* __restrict__ w,
                                                        cplx* __restrict__ ws, int B)
{
    __shared__ float4 LDSf4[4160];          // 66560 B
    char* LDS = (char*)LDSf4;
    cplx* W = (cplx*)LDS;                   // fp32 D/H matrix (aliases Yset)
    short* sh = (short*)LDS;                // bf16 planes
    float* red = (float*)(LDS + 65536);
    int t = threadIdx.x, blk = blockIdx.x;

    // ---- load coefficients into D-layout W[m][z] = c*( -i)^popc(m&z) ----
    float sumsq = 0.f;
    {
        const bool isW = (blk >= B);
        const float* src = isW ? (w + (size_t)(blk - B) * 4095)
                               : (x + (size_t)blk * IN_DIM);
        #pragma unroll
        for (int n = 0; n < 16; n++) {
            int p = t + TPB * n;
            float v = isW ? ((p == 0) ? 0.f : src[p - 1])
                          : ((p < IN_DIM) ? src[p] : 0.f);
            sumsq += v * v;
            int xm, zm; pauli_masks(p, xm, zm);
            W[(xm << 6) + zm] = pauli_phase(v, xm, zm);
        }
    }
    __syncthreads();

    // ---- Frobenius bound -> prescale s1 so ||B||_2 <= 8 ----
    red[t] = sumsq; __syncthreads();
    for (int off = 128; off >= 1; off >>= 1) { if (t < off) red[t] += red[t + off]; __syncthreads(); }
    float fro = sqrtf(64.f * red[0]);
    __syncthreads();
    int s1 = 0; { float nn = fro; while (nn > 8.f && s1 < 24) { nn *= 0.5f; s1++; } }
    float sc1 = exp2f((float)(-s1));

    // ---- WHT over z within each row m ----
    for (int st = 0; st < 6; st++) {
        int len = 1 << st;
        #pragma unroll
        for (int n = 0; n < 8; n++) {
            int qq = t + TPB * n;
            int m = qq >> 5, bf = qq & 31;
            int lo = bf & (len - 1), hi = bf >> st;
            int z0 = (hi << (st + 1)) | lo, z1 = z0 | len;
            cplx a = W[(m << 6) + z0], b = W[(m << 6) + z1];
            W[(m << 6) + z0] = make_float2(a.x + b.x, a.y + b.y);
            W[(m << 6) + z1] = make_float2(a.x - b.x, a.y - b.y);
        }
        __syncthreads();
    }

    // ---- gather then scatter: B[i][i^m] = -i*h_m(i)*2^-s1 -> bf16 planes ----
    cplx hv[16];
    #pragma unroll
    for (int n = 0; n < 16; n++) hv[n] = W[t + TPB * n];
    __syncthreads();
    #pragma unroll
    for (int n = 0; n < 16; n++) {
        int idx = t + TPB * n;
        int m = idx >> 6, i = idx & 63;
        float vr = hv[n].y * sc1, vi = -hv[n].x * sc1;
        int r = i, c = i ^ m;
        short rh = f2bf(vr), rl = f2bf(vr - bf2f(rh));
        short ih = f2bf(vi), il = f2bf(vi - bf2f(ih));
        int offY = idxSw(r, c);
        int offX = idxSw(c, r);
        sh[offY] = rh; sh[4096 + offY] = rl; sh[8192 + offY] = ih; sh[12288 + offY] = il;
        sh[16384 + offX] = rh; sh[16384 + 4096 + offX] = rl;
        sh[16384 + 8192 + offX] = ih; sh[16384 + 12288 + offX] = il;
    }
    __syncthreads();

    const int lane = t & 63, wv = t >> 6, li = lane & 15, q = lane >> 4;
    const int mh = wv & 1, nh = wv >> 1;
    const float4v z4 = {0.f, 0.f, 0.f, 0.f};
    float4v accRR[4], accII[4], accRI[4], accIR[4];
    float4v ure[4], uim[4];

    #define ZERO_ACC  _Pragma("unroll") for (int i2 = 0; i2 < 4; i2++) { accRR[i2]=z4; accII[i2]=z4; accRI[i2]=z4; accIR[i2]=z4; }

    // ---- mm1: B2 = B*B ----
    ZERO_ACC
    mm_mfma(sh, li, q, mh, nh, accRR, accII, accRI, accIR);
    float ss = 0.f;
    #pragma unroll
    for (int ti = 0; ti < 4; ti++) {
        ure[ti] = accRR[ti] - accII[ti];
        uim[ti] = accRI[ti] + accIR[ti];
        #pragma unroll
        for (int e = 0; e < 4; e++) ss += ure[ti][e]*ure[ti][e] + uim[ti][e]*uim[ti][e];
    }
    __syncthreads();                        // all mm1 LDS reads done

    // ---- Schatten-4: ||B||_2 <= sqrt(||B2||_F) -> ds extra scaling ----
    red[t] = ss; __syncthreads();
    for (int off = 128; off >= 1; off >>= 1) { if (t < off) red[t] += red[t + off]; __syncthreads(); }
    float bound = sqrtf(sqrtf(red[0]));
    int ds = 0; { float nn = bound; while (nn > 2.f && ds < 12) { nn *= 0.5f; ds++; } }
    const int s = s1 + ds;
    float dsc = exp2f((float)(-ds)), dsc2 = dsc * dsc;

    // ---- B tile (C-layout) for Horner combos; read before Yset overwritten ----
    float4v bre[4] = {z4, z4, z4, z4}, bim[4] = {z4, z4, z4, z4};
    gather_tile(sh, li, q, mh, nh, bre, bim);

    // ---- A2 = dsc^2 * B2 -> Xset (static Horner right operand) ----
    #pragma unroll
    for (int ti = 0; ti < 4; ti++) { ure[ti] *= dsc2; uim[ti] *= dsc2; }
    write_col(sh, li, q, mh, nh, ure, uim);
    __syncthreads();                        // B gathers complete before V6 write

    // ---- V6 = C12 I + C13*dsc*B -> Yset ----
    {
        float ca = C13f * dsc;
        #pragma unroll
        for (int ti = 0; ti < 4; ti++) { ure[ti] = ca * bre[ti]; uim[ti] = ca * bim[ti]; }
        adddiag(ure, C12f, li, q, mh, nh);
        write_row(sh, li, q, mh, nh, ure, uim);
    }
    __syncthreads();

    // ---- Horner: V_j = c2j I + c2j+1*dsc*B + V_{j+1}*A2, j = 5..0 ----
    const float cIc[6] = { 1.0f, 0.5f, C4f, C6f, C8f, C10f };
    const float cAc[6] = { 1.0f, C3f,  C5f, C7f, C9f, C11f };
    #pragma unroll
    for (int j = 5; j >= 0; j--) {
        ZERO_ACC
        mm_mfma(sh, li, q, mh, nh, accRR, accII, accRI, accIR);
        __syncthreads();
        float ca = cAc[j] * dsc, cI = cIc[j];
        #pragma unroll
        for (int ti = 0; ti < 4; ti++) {
            ure[ti] = accRR[ti] - accII[ti] + ca * bre[ti];
            uim[ti] = accRI[ti] + accIR[ti] + ca * bim[ti];
        }
        adddiag(ure, cI, li, q, mh, nh);
        write_row(sh, li, q, mh, nh, ure, uim);
        if (j == 0) write_col(sh, li, q, mh, nh, ure, uim);
        __syncthreads();
    }

    // ---- s squarings: U <- U*U ----
    for (int sq = 0; sq < s; sq++) {
        ZERO_ACC
        mm_mfma(sh, li, q, mh, nh, accRR, accII, accRI, accIR);
        __syncthreads();
        #pragma unroll
        for (int ti = 0; ti < 4; ti++) {
            ure[ti] = accRR[ti] - accII[ti];
            uim[ti] = accRI[ti] + accIR[ti];
        }
        if (sq < s - 1) {
            write_row(sh, li, q, mh, nh, ure, uim);
            write_col(sh, li, q, mh, nh, ure, uim);
            __syncthreads();
        }
    }
    #undef ZERO_ACC

    // ---- U -> ws slot (fp32, plain-swizzled cols for matvec_row) ----
    cplx* dst = ws + ((size_t)blk << 12);
    #pragma unroll
    for (int dm = 0; dm < 2; dm++)
    #pragma unroll
    for (int dn = 0; dn < 2; dn++) {
        int ti = dm * 2 + dn;
        int c = ((nh * 2 + dn) << 4) + li;
        int cs = c ^ (((c >> 4) & 1) << 1);
        #pragma unroll
        for (int reg = 0; reg < 4; reg++) {
            int r = ((mh * 2 + dm) << 4) + q * 4 + reg;
            dst[(r << 6) + cs] = make_float2(ure[ti][reg], uim[ti][reg]);
        }
    }
}

// acc = M[i][:] . pin ; M plain-swizzled; chunk rotation spreads banks
__device__ __forceinline__ cplx matvec_row(const cplx* __restrict__ M,
                                           const cplx* __restrict__ pin, int i)
{
    float ax = 0.f, ay = 0.f;
    const float4* Mr = (const float4*)(M + (i << 6));
    #pragma unroll
    for (int mm = 0; mm < 16; mm++) {
        int ch = (mm + (i & 15)) & 15;
        int b = (ch >> 2) & 1;
        float4 m01 = Mr[(ch << 1) + b];
        float4 m23 = Mr[(ch << 1) + 1 - b];
        const cplx* p = pin + (ch << 2);
        cplx p0 = p[0], p1 = p[1], p2 = p[2], p3 = p[3];
        ax = fmaf(m01.x, p0.x, fmaf(-m01.y, p0.y, ax));
        ay = fmaf(m01.x, p0.y, fmaf( m01.y, p0.x, ay));
        ax = fmaf(m01.z, p1.x, fmaf(-m01.w, p1.y, ax));
        ay = fmaf(m01.z, p1.y, fmaf( m01.w, p1.x, ay));
        ax = fmaf(m23.x, p2.x, fmaf(-m23.y, p2.y, ax));
        ay = fmaf(m23.x, p2.y, fmaf( m23.y, p2.x, ay));
        ax = fmaf(m23.z, p3.x, fmaf(-m23.w, p3.y, ax));
        ay = fmaf(m23.z, p3.y, fmaf( m23.w, p3.x, ay));
    }
    return make_float2(ax, ay);
}

__global__ __launch_bounds__(TPB) void matvec_kernel(const cplx* __restrict__ ws,
                                                     const float* __restrict__ bias,
                                                     float* __restrict__ out, int B)
{
    __shared__ float4 Xs4[2048];
    __shared__ float4 Ys4[2048];
    __shared__ cplx psiA[64], psiB[64];
    cplx* X = (cplx*)Xs4;
    cplx* Y = (cplx*)Ys4;
    int t = threadIdx.x, b = blockIdx.x;
    {
        const float4* src = (const float4*)(ws + ((size_t)b << 12));
        float4* dst = (float4*)X;
        #pragma unroll
        for (int n = 0; n < 8; n++) dst[n * TPB + t] = src[n * TPB + t];
    }
    if (t < 64) psiA[t] = make_float2(t == 0 ? 1.f : 0.f, 0.f);
    __syncthreads();
    for (int r = 0; r < NREPS; r++) {
        const float4* src = (const float4*)(ws + ((size_t)(B + r) << 12));
        float4* dstY = (float4*)Y;
        #pragma unroll
        for (int n = 0; n < 8; n++) dstY[n * TPB + t] = src[n * TPB + t];
        __syncthreads();
        if (t < 64) psiB[t] = matvec_row(X, psiA, t);
        __syncthreads();
        if (t < 64) psiA[t] = matvec_row(Y, psiB, t);
        __syncthreads();
    }
    if (t < 64) {
        cplx pv = psiA[t];
        out[(b << 6) + t] = fmaf(pv.x, pv.x, fmaf(pv.y, pv.y, bias[t]));
    }
}

extern "C" void kernel_launch(void* const* d_in, const int* in_sizes, int n_in,
                              void* d_out, int out_size, void* d_ws, size_t ws_size,
                              hipStream_t stream)
{
    const float* x    = (const float*)d_in[0];
    const float* w    = (const float*)d_in[1];
    const float* bias = (const float*)d_in[2];
    float* out = (float*)d_out;
    cplx* ws   = (cplx*)d_ws;               // (B+4) * 32 KB ≈ 16.9 MB

    int B = in_sizes[0] / IN_DIM;           // 512

    hipLaunchKernelGGL(expm_mfma_kernel, dim3(B + NREPS), dim3(TPB), 0, stream, x, w, ws, B);
    hipLaunchKernelGGL(matvec_kernel,    dim3(B),         dim3(TPB), 0, stream, ws, bias, out, B);
}

// Round 6
// 161.098 us; speedup vs baseline: 3.8039x; 1.0313x over previous
//
#include <hip/hip_runtime.h>
#include <math.h>

typedef float2 cplx;
typedef __attribute__((ext_vector_type(8))) short short8v;
typedef __attribute__((ext_vector_type(4))) short short4v;
typedef __attribute__((ext_vector_type(4))) float float4v;

#define TPB 256
#define IN_DIM 4000
#define NREPS 4

// 1/k! 0..15
#define C0f  1.0f
#define C1f  1.0f
#define C2f  0.5f
#define C3f  0.16666667f
#define C4f  0.041666668f
#define C5f  8.3333333e-3f
#define C6f  1.3888889e-3f
#define C7f  1.9841270e-4f
#define C8f  2.4801587e-5f
#define C9f  2.7557319e-6f
#define C10f 2.7557319e-7f
#define C11f 2.5052108e-8f
#define C12f 2.0876757e-9f
#define C13f 1.6059044e-10f
#define C14f 1.1470746e-11f
#define C15f 7.6471637e-13f

#define MFMA(A,B,C) __builtin_amdgcn_mfma_f32_16x16x32_bf16((A),(B),(C),0,0,0)

// ---------------------------------------------------------------------------
// LDS (expm): S0 = bf16 planes {rh,rl,ih,il} of the "row-major" matrix
// ([0,32K)); S1 = second plane-set ([32K,64K)) holding A2 (Horner) or U^T
// (squarings); the fp32 D/H matrix W aliases S1 during load/WHT. red[8] at 64K.
// Plane layout: elem (a,b) at idxSw(a,b) — rows of 8 16B-chunks rotated by row.
// mfma tiling (verified r5): wave wv -> 32x32 quadrant (mh=wv&1, nh=wv>>1),
// 2x2 16x16 tiles; lane: li=lane&15, q=lane>>4.
// A-frag: M[m=li][k=q*8+j] (row-contig); B-frag: M2[k][n=li] = row n of M2^T.
// Structure: B anti-Herm (B^T = -conj B -> neg-re fixup), A2 Herm (neg-im),
// squarings keep explicit U^T copy in S1.
// ---------------------------------------------------------------------------

__device__ __forceinline__ int idxSw(int a, int b) {
    return (a << 6) + ((((b >> 3) + a) & 7) << 3) + (b & 7);
}
__device__ __forceinline__ short f2bf(float f) {   // RNE to bf16
    unsigned u = __float_as_uint(f);
    return (short)((u + 0x7FFF + ((u >> 16) & 1)) >> 16);
}
__device__ __forceinline__ float bf2f(short s) {
    return __uint_as_float(((unsigned)(unsigned short)s) << 16);
}
__device__ __forceinline__ short8v neg8(short8v a) {
    int4 u; __builtin_memcpy(&u, &a, 16);
    u.x ^= 0x80008000; u.y ^= 0x80008000; u.z ^= 0x80008000; u.w ^= 0x80008000;
    short8v r; __builtin_memcpy(&r, &u, 16); return r;
}

// C = L * R. A-frags from As rows. B-frags from Bs rows (Bs holds R^T or a
// Hermitian-symmetric stand-in). MODE: 0 plain, 1 negate re (anti-Herm R),
// 2 negate im (Herm R).
template<int MODE>
__device__ __forceinline__ void mm_mfma(const short* __restrict__ As,
                                        const short* __restrict__ Bs,
                                        int li, int q, int mh, int nh,
                                        float4v* __restrict__ accR,
                                        float4v* __restrict__ accI)
{
    #pragma unroll
    for (int ks = 0; ks < 2; ks++) {
        const int ch = ks * 4 + q;
        short8v arh[2], arl[2], aih[2], ail[2], nih[2], nil_[2];
        #pragma unroll
        for (int dm = 0; dm < 2; dm++) {
            int r = ((mh * 2 + dm) << 4) + li;
            int off = (r << 6) + (((ch + r) & 7) << 3);
            arh[dm] = *(const short8v*)(As + off);
            arl[dm] = *(const short8v*)(As + 4096 + off);
            aih[dm] = *(const short8v*)(As + 8192 + off);
            ail[dm] = *(const short8v*)(As + 12288 + off);
            nih[dm] = neg8(aih[dm]);
            nil_[dm] = neg8(ail[dm]);
        }
        #pragma unroll
        for (int dn = 0; dn < 2; dn++) {
            int n = ((nh * 2 + dn) << 4) + li;
            int off = (n << 6) + (((ch + n) & 7) << 3);
            short8v brh = *(const short8v*)(Bs + off);
            short8v brl = *(const short8v*)(Bs + 4096 + off);
            short8v bih = *(const short8v*)(Bs + 8192 + off);
            short8v bil = *(const short8v*)(Bs + 12288 + off);
            if (MODE == 1) { brh = neg8(brh); brl = neg8(brl); }
            if (MODE == 2) { bih = neg8(bih); bil = neg8(bil); }
            #pragma unroll
            for (int dm = 0; dm < 2; dm++) {
                int ti = dm * 2 + dn;
                accR[ti] = MFMA(arh[dm], brh, accR[ti]);
                accR[ti] = MFMA(arh[dm], brl, accR[ti]);
                accR[ti] = MFMA(arl[dm], brh, accR[ti]);
                accR[ti] = MFMA(nih[dm], bih, accR[ti]);
                accR[ti] = MFMA(nih[dm], bil, accR[ti]);
                accR[ti] = MFMA(nil_[dm], bih, accR[ti]);
                accI[ti] = MFMA(arh[dm], bih, accI[ti]);
                accI[ti] = MFMA(arh[dm], bil, accI[ti]);
                accI[ti] = MFMA(arl[dm], bih, accI[ti]);
                accI[ti] = MFMA(aih[dm], brh, accI[ti]);
                accI[ti] = MFMA(aih[dm], brl, accI[ti]);
                accI[ti] = MFMA(ail[dm], brh, accI[ti]);
            }
        }
    }
}

// C-layout tile -> row-major planes of S (b16 scatter)
__device__ __forceinline__ void write_row(short* __restrict__ S, int li, int q,
                                          int mh, int nh,
                                          const float4v* cre, const float4v* cim)
{
    #pragma unroll
    for (int dm = 0; dm < 2; dm++)
    #pragma unroll
    for (int dn = 0; dn < 2; dn++) {
        int ti = dm * 2 + dn;
        int c = ((nh * 2 + dn) << 4) + li;
        #pragma unroll
        for (int reg = 0; reg < 4; reg++) {
            int r = ((mh * 2 + dm) << 4) + q * 4 + reg;
            int off = idxSw(r, c);
            float vr = cre[ti][reg], vi = cim[ti][reg];
            short rh = f2bf(vr), rl = f2bf(vr - bf2f(rh));
            short ih = f2bf(vi), il = f2bf(vi - bf2f(ih));
            S[off] = rh; S[4096 + off] = rl; S[8192 + off] = ih; S[12288 + off] = il;
        }
    }
}

// C-layout tile -> transposed locations (row-major M^T) in S (b64 packed)
__device__ __forceinline__ void write_rowT(short* __restrict__ S, int li, int q,
                                           int mh, int nh,
                                           const float4v* cre, const float4v* cim)
{
    #pragma unroll
    for (int dm = 0; dm < 2; dm++)
    #pragma unroll
    for (int dn = 0; dn < 2; dn++) {
        int ti = dm * 2 + dn;
        int c = ((nh * 2 + dn) << 4) + li;
        int k0 = ((mh * 2 + dm) << 4) + q * 4;
        int off = idxSw(c, k0);
        short4v rh, rl, ih, il;
        #pragma unroll
        for (int reg = 0; reg < 4; reg++) {
            float vr = cre[ti][reg], vi = cim[ti][reg];
            short h1 = f2bf(vr); rh[reg] = h1; rl[reg] = f2bf(vr - bf2f(h1));
            short h2 = f2bf(vi); ih[reg] = h2; il[reg] = f2bf(vi - bf2f(h2));
        }
        *(short4v*)(S + off) = rh;
        *(short4v*)(S + 4096 + off) = rl;
        *(short4v*)(S + 8192 + off) = ih;
        *(short4v*)(S + 12288 + off) = il;
    }
}

// gather lane's C-layout tile of the matrix in S (hi+lo reconstruct)
__device__ __forceinline__ void gather_tile(const short* __restrict__ S, int li, int q,
                                            int mh, int nh, float4v* bre, float4v* bim)
{
    #pragma unroll
    for (int dm = 0; dm < 2; dm++)
    #pragma unroll
    for (int dn = 0; dn < 2; dn++) {
        int ti = dm * 2 + dn;
        int c = ((nh * 2 + dn) << 4) + li;
        #pragma unroll
        for (int reg = 0; reg < 4; reg++) {
            int r = ((mh * 2 + dm) << 4) + q * 4 + reg;
            int off = idxSw(r, c);
            bre[ti][reg] = bf2f(S[off]) + bf2f(S[4096 + off]);
            bim[ti][reg] = bf2f(S[8192 + off]) + bf2f(S[12288 + off]);
        }
    }
}

__device__ __forceinline__ void adddiag(float4v* ure, float cI, int li, int q, int mh, int nh)
{
    #pragma unroll
    for (int dm = 0; dm < 2; dm++)
    #pragma unroll
    for (int dn = 0; dn < 2; dn++) {
        if (2 * mh + dm == 2 * nh + dn) {
            #pragma unroll
            for (int e = 0; e < 4; e++)
                if (li == q * 4 + e) ure[dm * 2 + dn][e] += cI;
        }
    }
}

// Pauli index p -> (xmask, zmask); D-value = c * (-i)^popc(x&z)
__device__ __forceinline__ void pauli_masks(int p, int& xm, int& zm) {
    xm = 0; zm = 0;
    #pragma unroll
    for (int k = 0; k < 6; k++) {
        int lo = (p >> (2 * k)) & 1;
        int hi = (p >> (2 * k + 1)) & 1;
        zm |= hi << k;
        xm |= (hi ^ lo) << k;
    }
}
__device__ __forceinline__ cplx pauli_phase(float v, int xm, int zm) {
    int ny = __popc(xm & zm) & 3;
    if (ny == 0) return make_float2(v, 0.f);
    if (ny == 1) return make_float2(0.f, -v);
    if (ny == 2) return make_float2(-v, 0.f);
    return make_float2(0.f, v);
}

// ===== expm: one block per Hamiltonian; blocks [0,B) = Ud, [B,B+4) = Up =====
__global__ __launch_bounds__(TPB) void expm_mfma_kernel(const float* __restrict__ x,
                                                        const float* __restrict__ w,
                                                        cplx* __restrict__ ws, int B)
{
    __shared__ float4 LDSf4[4098];          // 65568 B
    char* LDS = (char*)LDSf4;
    short* S0 = (short*)LDS;                // bf16 planes, row-major matrix
    short* S1 = S0 + 16384;                 // A2 / U^T planes
    cplx* W = (cplx*)(LDS + 32768);         // fp32 D matrix (aliases S1)
    float* red = (float*)(LDS + 65536);     // red[0..7]
    const int t = threadIdx.x, blk = blockIdx.x;
    const int lane = t & 63, wv = t >> 6;

    // ---- load coefficients -> W[m=xmask][z=zmask]; wave-reduced sumsq ----
    float sumsq = 0.f;
    {
        const bool isW = (blk >= B);
        const float* src = isW ? (w + (size_t)(blk - B) * 4095)
                               : (x + (size_t)blk * IN_DIM);
        #pragma unroll
        for (int n = 0; n < 16; n++) {
            int p = t + TPB * n;
            float v = isW ? ((p == 0) ? 0.f : src[p - 1])
                          : ((p < IN_DIM) ? src[p] : 0.f);
            sumsq += v * v;
            int xm, zm; pauli_masks(p, xm, zm);
            W[(xm << 6) + zm] = pauli_phase(v, xm, zm);
        }
        #pragma unroll
        for (int d = 32; d >= 1; d >>= 1) sumsq += __shfl_xor(sumsq, d, 64);
        if (lane == 0) red[wv] = sumsq;
    }
    __syncthreads();

    // ---- Frobenius prescale: ||B||_2 <= fro/2^s1 in (4,8] ----
    float fro = sqrtf(64.f * (red[0] + red[1] + red[2] + red[3]));
    int s1 = 0; { float nn = fro; while (nn > 8.f && s1 < 24) { nn *= 0.5f; s1++; } }
    float sc1 = exp2f((float)(-s1));

    // ---- in-register WHT: lane = z-index, 16 rows per wave ----
    cplx hv[16];
    #pragma unroll
    for (int rr = 0; rr < 16; rr++) hv[rr] = W[(((wv << 4) + rr) << 6) + lane];
    #pragma unroll
    for (int d = 1; d < 64; d <<= 1) {
        float sg = (lane & d) ? -1.f : 1.f;
        #pragma unroll
        for (int rr = 0; rr < 16; rr++) {
            float px = __shfl_xor(hv[rr].x, d, 64);
            float py = __shfl_xor(hv[rr].y, d, 64);
            hv[rr].x = fmaf(sg, hv[rr].x, px);
            hv[rr].y = fmaf(sg, hv[rr].y, py);
        }
    }
    __syncthreads();            // all W reads done before S0 writes (no alias, but cheap safety for S1-aliased W)

    // ---- scatter B[l][l^m] = -i*h_m(l)*sc1 -> S0 planes only ----
    #pragma unroll
    for (int rr = 0; rr < 16; rr++) {
        int m = (wv << 4) + rr;
        int c = lane ^ m;
        float vr = hv[rr].y * sc1, vi = -hv[rr].x * sc1;
        short rh = f2bf(vr), rl = f2bf(vr - bf2f(rh));
        short ih = f2bf(vi), il = f2bf(vi - bf2f(ih));
        int off = idxSw(lane, c);
        S0[off] = rh; S0[4096 + off] = rl; S0[8192 + off] = ih; S0[12288 + off] = il;
    }
    __syncthreads();

    const int li = lane & 15, q = lane >> 4;
    const int mh = wv & 1, nh = wv >> 1;
    const float4v z4 = {0.f, 0.f, 0.f, 0.f};
    float4v accR[4], accI[4];
    #define ZERO_ACC _Pragma("unroll") for (int i2 = 0; i2 < 4; i2++) { accR[i2]=z4; accI[i2]=z4; }

    // ---- mm1: B2 = B*B (B-frags from S0 via anti-Hermitian neg-re) ----
    ZERO_ACC
    mm_mfma<1>(S0, S0, li, q, mh, nh, accR, accI);
    float ss = 0.f;
    #pragma unroll
    for (int ti = 0; ti < 4; ti++)
        #pragma unroll
        for (int e = 0; e < 4; e++)
            ss += accR[ti][e]*accR[ti][e] + accI[ti][e]*accI[ti][e];
    #pragma unroll
    for (int d = 32; d >= 1; d >>= 1) ss += __shfl_xor(ss, d, 64);
    if (lane == 0) red[4 + wv] = ss;
    __syncthreads();                        // mm1 reads done; red2 visible

    // ---- Schatten-4 bound -> extra halvings; theta = 3.4 ----
    float bound = sqrtf(sqrtf(red[4] + red[5] + red[6] + red[7]));
    int ds = 0; { float nn = bound; while (nn > 3.4f && ds < 12) { nn *= 0.5f; ds++; } }
    const int s = s1 + ds;
    float dsc = exp2f((float)(-ds)), dsc2 = dsc * dsc;

    // ---- B tile (C-layout) for Horner combos ----
    float4v bre[4], bim[4];
    gather_tile(S0, li, q, mh, nh, bre, bim);
    __syncthreads();                        // gathers done before S0 overwrite

    // ---- S1 <- A2 = dsc^2*B2 (row-major; Hermitian), S0 <- V7 = c14 I + c15 A ----
    float4v ure[4], uim[4];
    #pragma unroll
    for (int ti = 0; ti < 4; ti++) { ure[ti] = accR[ti] * dsc2; uim[ti] = accI[ti] * dsc2; }
    write_row(S1, li, q, mh, nh, ure, uim);
    {
        float ca = C15f * dsc;
        #pragma unroll
        for (int ti = 0; ti < 4; ti++) { ure[ti] = ca * bre[ti]; uim[ti] = ca * bim[ti]; }
        adddiag(ure, C14f, li, q, mh, nh);
        write_row(S0, li, q, mh, nh, ure, uim);
    }
    __syncthreads();

    // ---- Horner: V_j = cI_j I + cA_j A + V_{j+1}*A2, j = 6..0 ----
    const float cIc[7] = { C0f, C2f, C4f, C6f, C8f, C10f, C12f };
    const float cAc[7] = { C1f, C3f, C5f, C7f, C9f, C11f, C13f };
    for (int j = 6; j >= 0; j--) {
        ZERO_ACC
        mm_mfma<2>(S0, S1, li, q, mh, nh, accR, accI);   // V * A2 (Herm neg-im)
        __syncthreads();
        float ca = cAc[j] * dsc, cI = cIc[j];
        #pragma unroll
        for (int ti = 0; ti < 4; ti++) {
            ure[ti] = accR[ti] + ca * bre[ti];
            uim[ti] = accI[ti] + ca * bim[ti];
        }
        adddiag(ure, cI, li, q, mh, nh);
        write_row(S0, li, q, mh, nh, ure, uim);
        __syncthreads();
    }
    // regs ure/uim = U; S0 = U

    // ---- s squarings: U <- U*U (U^T maintained in S1) ----
    write_rowT(S1, li, q, mh, nh, ure, uim);
    __syncthreads();
    for (int sq = 0; sq < s; sq++) {
        ZERO_ACC
        mm_mfma<0>(S0, S1, li, q, mh, nh, accR, accI);
        __syncthreads();
        #pragma unroll
        for (int ti = 0; ti < 4; ti++) { ure[ti] = accR[ti]; uim[ti] = accI[ti]; }
        if (sq < s - 1) {
            write_row(S0, li, q, mh, nh, ure, uim);
            write_rowT(S1, li, q, mh, nh, ure, uim);
            __syncthreads();
        }
    }
    #undef ZERO_ACC

    // ---- U -> ws slot (fp32, plain-swizzled cols for matvec) ----
    cplx* dst = ws + ((size_t)blk << 12);
    #pragma unroll
    for (int dm = 0; dm < 2; dm++)
    #pragma unroll
    for (int dn = 0; dn < 2; dn++) {
        int ti = dm * 2 + dn;
        int c = ((nh * 2 + dn) << 4) + li;
        int cs = c ^ (((c >> 4) & 1) << 1);
        #pragma unroll
        for (int reg = 0; reg < 4; reg++) {
            int r = ((mh * 2 + dm) << 4) + q * 4 + reg;
            dst[(r << 6) + cs] = make_float2(ure[ti][reg], uim[ti][reg]);
        }
    }
}

// partial dot: rows i, chunk-group g of 4 (rotated for bank spread)
__device__ __forceinline__ cplx matvec_partial(const cplx* __restrict__ M,
                                               const cplx* __restrict__ pin,
                                               int i, int g)
{
    float ax = 0.f, ay = 0.f;
    const float4* Mr = (const float4*)(M + (i << 6));
    #pragma unroll
    for (int c = 0; c < 4; c++) {
        int ch = ((g << 2) + c + (i & 15)) & 15;
        int b = (ch >> 2) & 1;
        float4 m01 = Mr[(ch << 1) + b];
        float4 m23 = Mr[(ch << 1) + 1 - b];
        const cplx* p = pin + (ch << 2);
        cplx p0 = p[0], p1 = p[1], p2 = p[2], p3 = p[3];
        ax = fmaf(m01.x, p0.x, fmaf(-m01.y, p0.y, ax));
        ay = fmaf(m01.x, p0.y, fmaf( m01.y, p0.x, ay));
        ax = fmaf(m01.z, p1.x, fmaf(-m01.w, p1.y, ax));
        ay = fmaf(m01.z, p1.y, fmaf( m01.w, p1.x, ay));
        ax = fmaf(m23.x, p2.x, fmaf(-m23.y, p2.y, ax));
        ay = fmaf(m23.x, p2.y, fmaf( m23.y, p2.x, ay));
        ax = fmaf(m23.z, p3.x, fmaf(-m23.w, p3.y, ax));
        ay = fmaf(m23.z, p3.y, fmaf( m23.w, p3.x, ay));
    }
    return make_float2(ax, ay);
}

__global__ __launch_bounds__(TPB) void matvec_kernel(const cplx* __restrict__ ws,
                                                     const float* __restrict__ bias,
                                                     float* __restrict__ out, int B)
{
    __shared__ float4 Xs4[2048];
    __shared__ float4 Ys4[2048];
    __shared__ cplx psiA[64], psiB[64];
    __shared__ cplx part[256];
    cplx* X = (cplx*)Xs4;
    cplx* Y = (cplx*)Ys4;
    const int t = threadIdx.x, b = blockIdx.x;
    const int i = t & 63, g = t >> 6;
    {
        const float4* src = (const float4*)(ws + ((size_t)b << 12));
        float4* dst = (float4*)X;
        #pragma unroll
        for (int n = 0; n < 8; n++) dst[n * TPB + t] = src[n * TPB + t];
    }
    if (t < 64) psiA[t] = make_float2(t == 0 ? 1.f : 0.f, 0.f);
    __syncthreads();

    for (int r = 0; r < NREPS; r++) {
        {   // stage Up[r] into Y (overlaps with Ud matvec below; fenced by barrier)
            const float4* src = (const float4*)(ws + ((size_t)(B + r) << 12));
            float4* dstY = (float4*)Y;
            #pragma unroll
            for (int n = 0; n < 8; n++) dstY[n * TPB + t] = src[n * TPB + t];
        }
        part[t] = matvec_partial(X, psiA, i, g);
        __syncthreads();
        if (t < 64) {
            cplx a0 = part[t], a1 = part[64 + t], a2 = part[128 + t], a3 = part[192 + t];
            psiB[t] = make_float2(a0.x + a1.x + a2.x + a3.x, a0.y + a1.y + a2.y + a3.y);
        }
        __syncthreads();
        part[t] = matvec_partial(Y, psiB, i, g);
        __syncthreads();
        if (t < 64) {
            cplx a0 = part[t], a1 = part[64 + t], a2 = part[128 + t], a3 = part[192 + t];
            psiA[t] = make_float2(a0.x + a1.x + a2.x + a3.x, a0.y + a1.y + a2.y + a3.y);
        }
        __syncthreads();
    }
    if (t < 64) {
        cplx pv = psiA[t];
        out[(b << 6) + t] = fmaf(pv.x, pv.x, fmaf(pv.y, pv.y, bias[t]));
    }
}

extern "C" void kernel_launch(void* const* d_in, const int* in_sizes, int n_in,
                              void* d_out, int out_size, void* d_ws, size_t ws_size,
                              hipStream_t stream)
{
    const float* x    = (const float*)d_in[0];
    const float* w    = (const float*)d_in[1];
    const float* bias = (const float*)d_in[2];
    float* out = (float*)d_out;
    cplx* ws   = (cplx*)d_ws;               // (B+4) * 32 KB ≈ 16.9 MB

    int B = in_sizes[0] / IN_DIM;           // 512

    hipLaunchKernelGGL(expm_mfma_kernel, dim3(B + NREPS), dim3(TPB), 0, stream, x, w, ws, B);
    hipLaunchKernelGGL(matvec_kernel,    dim3(B),         dim3(TPB), 0, stream, ws, bias, out, B);
}